// Round 1
// 628.435 us; speedup vs baseline: 1.2529x; 1.2529x over previous
//
#include <hip/hip_runtime.h>
#include <math.h>

#define NB 4
#define NH 32
#define NSQ 2048            // seq len
#define ND 128              // head dim
#define SPLIT 2
#define SCHUNK (NSQ / SPLIT)   // 1024
#define RB 64                  // rows per block-iteration
#define NITER (SCHUNK / RB)    // 16
#define NTHR 512

static constexpr size_t OUT_ELEMS = (size_t)NB * NH * NSQ * ND;        // 33554432
static constexpr size_t NS_OFF    = OUT_ELEMS;                         // new_states
static constexpr size_t NZ_OFF    = NS_OFF + (size_t)NB * NH * ND * ND; // new_z

// LDS (u32 units): lsq[64][132] | lsk[64][132] | skT[128][64] | vdT[128][64]
//                  | lz[128] | lgate[128] | lsqz[64] | lskz[64] | lnz[128]
static constexpr int LDS_BYTES = (2 * RB * 132 + 2 * ND * 64 + 3 * ND + 2 * RB) * 4; // 135168

typedef __attribute__((ext_vector_type(8))) short short8v;   // 8 x bf16 (4 VGPRs)
typedef __attribute__((ext_vector_type(4))) float f32x4;

#define MFMA16(a, b, c) __builtin_amdgcn_mfma_f32_16x16x32_bf16(a, b, c, 0, 0, 0)

__device__ __forceinline__ float4 elu1(float4 x) {
    // elu(x)+1 : x>0 -> x+1 ; x<=0 -> exp(x)
    float4 r;
    r.x = x.x > 0.f ? x.x + 1.f : __expf(x.x);
    r.y = x.y > 0.f ? x.y + 1.f : __expf(x.y);
    r.z = x.z > 0.f ? x.z + 1.f : __expf(x.z);
    r.w = x.w > 0.f ? x.w + 1.f : __expf(x.w);
    return r;
}

// split fp32 into truncated-bf16 hi/lo, packed as one u32 = [hi16 | lo16]
__device__ __forceinline__ unsigned int pack1(float x) {
    unsigned int bx = __float_as_uint(x);
    float lo = x - __uint_as_float(bx & 0xFFFF0000u);
    // bytes: [lo.b2, lo.b3, x.b2, x.b3]  -> low half = lo16, top half = hi16
    return __builtin_amdgcn_perm(bx, __float_as_uint(lo), 0x07060302u);
}
__device__ __forceinline__ float uph(unsigned int w) { return __uint_as_float(w & 0xFFFF0000u); }
__device__ __forceinline__ float upl(unsigned int w) { return __uint_as_float(w << 16); }

// 8 packed (hi|lo) words -> hi-frag / lo-frag (bf16x8 as short8)
__device__ __forceinline__ void unpack2(uint4 a, uint4 b, short8v& hi, short8v& lo) {
    union { unsigned int u[4]; short8v s; } H, L;
    H.u[0] = __builtin_amdgcn_perm(a.y, a.x, 0x07060302u);
    H.u[1] = __builtin_amdgcn_perm(a.w, a.z, 0x07060302u);
    H.u[2] = __builtin_amdgcn_perm(b.y, b.x, 0x07060302u);
    H.u[3] = __builtin_amdgcn_perm(b.w, b.z, 0x07060302u);
    L.u[0] = __builtin_amdgcn_perm(a.y, a.x, 0x05040100u);
    L.u[1] = __builtin_amdgcn_perm(a.w, a.z, 0x05040100u);
    L.u[2] = __builtin_amdgcn_perm(b.y, b.x, 0x05040100u);
    L.u[3] = __builtin_amdgcn_perm(b.w, b.z, 0x05040100u);
    hi = H.s; lo = L.s;
}

// 8 fp32 -> hi-frag / lo-frag
__device__ __forceinline__ void pack8(const float* x, short8v& hi, short8v& lo) {
    union { unsigned int u[4]; short8v s; } H, L;
    #pragma unroll
    for (int d = 0; d < 4; ++d) {
        unsigned int b0 = __float_as_uint(x[2 * d]);
        unsigned int b1 = __float_as_uint(x[2 * d + 1]);
        float l0 = x[2 * d]     - __uint_as_float(b0 & 0xFFFF0000u);
        float l1 = x[2 * d + 1] - __uint_as_float(b1 & 0xFFFF0000u);
        H.u[d] = __builtin_amdgcn_perm(b1, b0, 0x07060302u);
        L.u[d] = __builtin_amdgcn_perm(__float_as_uint(l1), __float_as_uint(l0), 0x07060302u);
    }
    hi = H.s; lo = L.s;
}

// Pre-init new_states = broadcast(init_mem), new_z = broadcast(init_z); main kernel atomicAdds partials.
extern "C" __global__ void cm_init(const float* __restrict__ mem0,
                                   const float* __restrict__ z0,
                                   float* __restrict__ out) {
    const int NSF4 = NB * NH * ND * ND / 4;  // 524288
    const int NZF4 = NB * NH * ND / 4;       // 4096
    int idx = blockIdx.x * 256 + threadIdx.x;
    if (idx < NSF4) {
        const int per_bh = ND * ND / 4;      // 4096
        int h = (idx / per_bh) % NH;
        int off = idx % per_bh;
        ((float4*)(out + NS_OFF))[idx] = ((const float4*)mem0)[h * per_bh + off];
    } else if (idx < NSF4 + NZF4) {
        int j = idx - NSF4;
        const int per_bh = ND / 4;           // 32
        int h = (j / per_bh) % NH;
        int off = j % per_bh;
        ((float4*)(out + NZ_OFF))[j] = ((const float4*)z0)[h * per_bh + off];
    }
}

extern "C" __global__ void __launch_bounds__(NTHR, 2)
cm_main(const float* __restrict__ q, const float* __restrict__ kin,
        const float* __restrict__ v, const float* __restrict__ attn,
        const float* __restrict__ betas, const float* __restrict__ mem0,
        const float* __restrict__ z0, float* __restrict__ out) {
    extern __shared__ unsigned int lds[];
    uint4* lsqT  = (uint4*)lds;               // [64][33] uint4, packed hi|lo sq
    uint4* lskT  = lsqT + RB * 33;            // [64][33]
    uint4* skT   = lskT + RB * 33;            // [128][16] swizzled, sk transposed
    uint4* vdT   = skT + ND * 16;             // [128][16] swizzled, vd transposed
    float* lz    = (float*)(vdT + ND * 16);   // [128]
    float* lgate = lz + ND;                   // [128]
    float* lsqz  = lgate + ND;                // [64]
    float* lskz  = lsqz + RB;                 // [64]
    float* lnz   = lskz + RB;                 // [128]

    const int t   = threadIdx.x;
    const int wg  = blockIdx.x;
    const int cch = wg % SPLIT;
    const int h   = (wg / SPLIT) % NH;
    const int b   = wg / (SPLIT * NH);

    if (t < ND) {
        lz[t] = z0[h * ND + t];
        float be = betas[h * ND + t];
        lgate[t] = 1.f / (1.f + __expf(-be));
        lnz[t] = 0.f;
    }

    const int lane = t & 63;
    const int l15  = lane & 15;     // MFMA: A-row / B-col / C-col
    const int l4   = lane >> 4;     // MFMA: k-group / C row-group
    const int wid  = t >> 6;        // wave 0..7
    const int wr   = wid >> 2;      // row half for GEMM1/2
    const int wc   = wid & 3;       // col quarter for GEMM1/2
    const int cc   = t & 31;        // staging column group
    const int rg2  = t >> 5;        // staging row group

    const size_t bh = (size_t)b * NH + h;
    const float4* q4 = (const float4*)(q   + bh * NSQ * ND);
    const float4* k4 = (const float4*)(kin + bh * NSQ * ND);
    const float*  vf = v    + bh * NSQ * ND;
    const float*  af = attn + bh * NSQ * ND;
    float*        of = out  + bh * NSQ * ND;

    // ---- persistent mem B-fragments in registers (hi/lo split), cols wc*32..+32 ----
    short8v bmh[2][4], bml[2][4];   // [ct][kt]
    {
        const float* mh = mem0 + (size_t)h * ND * ND;
        #pragma unroll
        for (int ct = 0; ct < 2; ++ct) {
            #pragma unroll
            for (int kt = 0; kt < 4; ++kt) {
                const int j  = wc * 32 + ct * 16 + l15;
                const int i0 = kt * 32 + l4 * 8;
                float x[8];
                #pragma unroll
                for (int e = 0; e < 8; ++e) x[e] = mh[(i0 + e) * ND + j];
                pack8(x, bmh[ct][kt], bml[ct][kt]);
            }
        }
    }

    f32x4 nsa[8];                   // ns rows wid*16..+16, cols ct*16..+16
    #pragma unroll
    for (int i = 0; i < 8; ++i) nsa[i] = (f32x4){0.f, 0.f, 0.f, 0.f};
    float4 nz = make_float4(0.f, 0.f, 0.f, 0.f);

    __syncthreads();

    for (int blk = 0; blk < NITER; ++blk) {
        const int s0 = cch * SCHUNK + blk * RB;

        // ---- phase A: stage sq/sk packed (row-major) + sk transposed ----
        uint4 kp[4];
        #pragma unroll
        for (int m = 0; m < 4; ++m) {
            const int r = rg2 * 4 + m;
            const size_t g = (size_t)(s0 + r) * 32 + cc;
            float4 sq = elu1(q4[g]);
            float4 sk = elu1(k4[g]);
            nz.x += sk.x; nz.y += sk.y; nz.z += sk.z; nz.w += sk.w;
            uint4 qp = make_uint4(pack1(sq.x), pack1(sq.y), pack1(sq.z), pack1(sq.w));
            kp[m]    = make_uint4(pack1(sk.x), pack1(sk.y), pack1(sk.z), pack1(sk.w));
            lsqT[r * 33 + cc] = qp;
            lskT[r * 33 + cc] = kp[m];
        }
        {   // in-thread 4x4 transpose -> skT[d][r], swizzled rf4 ^ ((d>>2)&7)
            const int swz = rg2 ^ (cc & 7);
            skT[(4 * cc + 0) * 16 + swz] = make_uint4(kp[0].x, kp[1].x, kp[2].x, kp[3].x);
            skT[(4 * cc + 1) * 16 + swz] = make_uint4(kp[0].y, kp[1].y, kp[2].y, kp[3].y);
            skT[(4 * cc + 2) * 16 + swz] = make_uint4(kp[0].z, kp[1].z, kp[2].z, kp[3].z);
            skT[(4 * cc + 3) * 16 + swz] = make_uint4(kp[0].w, kp[1].w, kp[2].w, kp[3].w);
        }
        __syncthreads();

        // ---- phase B: prefetch attn/v, z-dots (waves 0-1), GEMM1/2 on MFMA ----
        float pav[2][2][4], pvv[2][2][4];
        #pragma unroll
        for (int tr = 0; tr < 2; ++tr)
            #pragma unroll
            for (int ct = 0; ct < 2; ++ct) {
                const int col = wc * 32 + ct * 16 + l15;
                #pragma unroll
                for (int rg = 0; rg < 4; ++rg) {
                    const int r = wr * 32 + tr * 16 + l4 * 4 + rg;
                    const size_t off = (size_t)(s0 + r) * ND + col;
                    pav[tr][ct][rg] = af[off];
                    pvv[tr][ct][rg] = vf[off];
                }
            }

        if (t < 2 * RB) {
            const int r = t & (RB - 1);
            const uint4* src = (t < RB) ? lsqT : lskT;
            float acc = 0.f;
            #pragma unroll 8
            for (int d4 = 0; d4 < 32; ++d4) {
                uint4 pw = src[r * 33 + d4];
                float4 zz = ((const float4*)lz)[d4];
                acc = fmaf(uph(pw.x) + upl(pw.x), zz.x, acc);
                acc = fmaf(uph(pw.y) + upl(pw.y), zz.y, acc);
                acc = fmaf(uph(pw.z) + upl(pw.z), zz.z, acc);
                acc = fmaf(uph(pw.w) + upl(pw.w), zz.w, acc);
            }
            if (t < RB) lsqz[r] = acc; else lskz[r] = acc;
        }

        f32x4 mo[2][2], rt[2][2];
        #pragma unroll
        for (int a_ = 0; a_ < 2; ++a_)
            #pragma unroll
            for (int b_ = 0; b_ < 2; ++b_) {
                mo[a_][b_] = (f32x4){0.f, 0.f, 0.f, 0.f};
                rt[a_][b_] = (f32x4){0.f, 0.f, 0.f, 0.f};
            }

        #pragma unroll
        for (int kt = 0; kt < 4; ++kt) {
            #pragma unroll
            for (int tr = 0; tr < 2; ++tr) {
                const int r  = wr * 32 + tr * 16 + l15;
                const int c4 = kt * 8 + 2 * l4;
                short8v aqh, aql, akh, akl;
                unpack2(lsqT[r * 33 + c4], lsqT[r * 33 + c4 + 1], aqh, aql);
                unpack2(lskT[r * 33 + c4], lskT[r * 33 + c4 + 1], akh, akl);
                #pragma unroll
                for (int ct = 0; ct < 2; ++ct) {
                    mo[tr][ct] = MFMA16(aqh, bmh[ct][kt], mo[tr][ct]);
                    mo[tr][ct] = MFMA16(aql, bmh[ct][kt], mo[tr][ct]);
                    mo[tr][ct] = MFMA16(aqh, bml[ct][kt], mo[tr][ct]);
                    rt[tr][ct] = MFMA16(akh, bmh[ct][kt], rt[tr][ct]);
                    rt[tr][ct] = MFMA16(akl, bmh[ct][kt], rt[tr][ct]);
                    rt[tr][ct] = MFMA16(akh, bml[ct][kt], rt[tr][ct]);
                }
            }
        }
        __syncthreads();

        // ---- phase C: epilogue: out = gate*mo/sqz + (1-gate)*attn ; vd -> vdT ----
        float isq[2][4], isk[2][4];
        #pragma unroll
        for (int tr = 0; tr < 2; ++tr)
            #pragma unroll
            for (int rg = 0; rg < 4; ++rg) {
                const int r = wr * 32 + tr * 16 + l4 * 4 + rg;
                isq[tr][rg] = 1.f / lsqz[r];
                isk[tr][rg] = 1.f / lskz[r];
            }
        #pragma unroll
        for (int tr = 0; tr < 2; ++tr) {
            const int rf4 = wr * 8 + tr * 4 + l4;
            #pragma unroll
            for (int ct = 0; ct < 2; ++ct) {
                const int col = wc * 32 + ct * 16 + l15;
                const float g = lgate[col];
                unsigned int pk[4];
                #pragma unroll
                for (int rg = 0; rg < 4; ++rg) {
                    const int r = wr * 32 + tr * 16 + l4 * 4 + rg;
                    const size_t off = (size_t)(s0 + r) * ND + col;
                    const float av = pav[tr][ct][rg];
                    const float mv = mo[tr][ct][rg] * isq[tr][rg];
                    of[off] = fmaf(g, mv - av, av);
                    const float vd = fmaf(-isk[tr][rg], rt[tr][ct][rg], pvv[tr][ct][rg]);
                    pk[rg] = pack1(vd);
                }
                vdT[col * 16 + (rf4 ^ ((col >> 2) & 7))] = make_uint4(pk[0], pk[1], pk[2], pk[3]);
            }
        }
        __syncthreads();

        // ---- phase D: GEMM3: ns += sk^T @ vd (MFMA, transposed operands) ----
        #pragma unroll
        for (int kt = 0; kt < 2; ++kt) {
            const int dA = wid * 16 + l15;
            const int sA = (dA >> 2) & 7;
            const int h2 = kt * 8 + 2 * l4;
            short8v ah, al;
            unpack2(skT[dA * 16 + (h2 ^ sA)], skT[dA * 16 + ((h2 + 1) ^ sA)], ah, al);
            #pragma unroll
            for (int ct = 0; ct < 8; ++ct) {
                const int dB = ct * 16 + l15;
                const int sB = (dB >> 2) & 7;
                short8v bhv, blv;
                unpack2(vdT[dB * 16 + (h2 ^ sB)], vdT[dB * 16 + ((h2 + 1) ^ sB)], bhv, blv);
                nsa[ct] = MFMA16(ah, bhv, nsa[ct]);
                nsa[ct] = MFMA16(al, bhv, nsa[ct]);
                nsa[ct] = MFMA16(ah, blv, nsa[ct]);
            }
        }
        __syncthreads();
    }

    // ---- writeback new_states partials ----
    float* nso = out + NS_OFF + bh * ND * ND;
    #pragma unroll
    for (int ct = 0; ct < 8; ++ct) {
        #pragma unroll
        for (int rg = 0; rg < 4; ++rg) {
            const int i = wid * 16 + l4 * 4 + rg;
            const int j = ct * 16 + l15;
            atomicAdd(nso + (size_t)i * ND + j, nsa[ct][rg]);
        }
    }
    // ---- writeback new_z partials ----
    atomicAdd(&lnz[cc * 4 + 0], nz.x);
    atomicAdd(&lnz[cc * 4 + 1], nz.y);
    atomicAdd(&lnz[cc * 4 + 2], nz.z);
    atomicAdd(&lnz[cc * 4 + 3], nz.w);
    __syncthreads();
    if (t < ND) atomicAdd(out + NZ_OFF + bh * ND + t, lnz[t]);
}

extern "C" void kernel_launch(void* const* d_in, const int* in_sizes, int n_in,
                              void* d_out, int out_size, void* d_ws, size_t ws_size,
                              hipStream_t stream) {
    const float* q     = (const float*)d_in[0];
    const float* k     = (const float*)d_in[1];
    const float* v     = (const float*)d_in[2];
    const float* attn  = (const float*)d_in[3];
    const float* betas = (const float*)d_in[4];
    const float* mem0  = (const float*)d_in[5];
    const float* z0    = (const float*)d_in[6];
    float* out = (float*)d_out;

    hipFuncSetAttribute((const void*)cm_main,
                        hipFuncAttributeMaxDynamicSharedMemorySize, LDS_BYTES);

    const int initF4 = NB * NH * ND * ND / 4 + NB * NH * ND / 4;  // 528384
    cm_init<<<(initF4 + 255) / 256, 256, 0, stream>>>(mem0, z0, out);
    cm_main<<<NB * NH * SPLIT, NTHR, LDS_BYTES, stream>>>(q, k, v, attn, betas, mem0, z0, out);
}